// Round 1
// baseline (889.268 us; speedup 1.0000x reference)
//
#include <hip/hip_runtime.h>
#include <cstdint>

typedef unsigned long long u64;
typedef unsigned int u32;

#define B_ 4
#define N_ 3600
#define C_ 16
#define NW_ 57        // ceil(N/64) words of adjacency/valid bitmask
#define NPAD_ 3648    // NW_*64
#define NSORT_ 4096   // bitonic size
#define NMS_THRE_ 0.4f

// ---------------------------------------------------------------------------
// K1: per image, per row i: adjacency bitmask (57 u64 words) via wave ballot,
// and adj_con[i][c] = max over adjacent j of con[j][c] (init 0 to match
// where(adj, con, 0)). One wave per row, 4 rows per 256-thread block.
// ---------------------------------------------------------------------------
__global__ __launch_bounds__(256) void k_adj(const float* __restrict__ boxes,
                                             const float* __restrict__ con,
                                             u64* __restrict__ adj,
                                             float* __restrict__ adjcon) {
#pragma clang fp contract(off)
    __shared__ float sx1[NPAD_], sy1[NPAD_], sx2[NPAD_], sy2[NPAD_];
    const int tid  = threadIdx.x;
    const int lane = tid & 63;
    const int wv   = tid >> 6;
    const int g    = blockIdx.x;              // 0 .. B*N/4-1
    const int b    = g / (N_ / 4);
    const int r0   = (g % (N_ / 4)) * 4;

    for (int j = tid; j < NPAD_; j += 256) {
        float x1 = 0.f, y1 = 0.f, x2 = 0.f, y2 = 0.f;
        if (j < N_) {
            const float4 bx = reinterpret_cast<const float4*>(boxes)[(size_t)b * N_ + j];
            x1 = bx.x - bx.z * 0.5f;   // cx - w/2
            y1 = bx.y - bx.w * 0.5f;
            x2 = x1 + bx.z;            // x1 + w  (exact reference op order)
            y2 = y1 + bx.w;
        }
        sx1[j] = x1; sy1[j] = y1; sx2[j] = x2; sy2[j] = y2;
    }
    __syncthreads();

    const int   i   = r0 + wv;
    const float x1i = sx1[i], y1i = sy1[i], x2i = sx2[i], y2i = sy2[i];
    const float ai  = (x2i - x1i) * (y2i - y1i);

    float cm[C_];
#pragma unroll
    for (int k = 0; k < C_; ++k) cm[k] = 0.0f;

    for (int t = 0; t < NW_; ++t) {
        const int   j   = t * 64 + lane;
        const float x1j = sx1[j], y1j = sy1[j], x2j = sx2[j], y2j = sy2[j];
        const float aj  = (x2j - x1j) * (y2j - y1j);
        const float ltx = fmaxf(x1i, x1j);
        const float lty = fmaxf(y1i, y1j);
        const float rbx = fminf(x2i, x2j);
        const float rby = fminf(y2i, y2j);
        const float whx = fmaxf(rbx - ltx, 0.0f);
        const float why = fmaxf(rby - lty, 0.0f);
        const float inter = whx * why;
        const float denom = (ai + aj) - inter;
        const float iou   = inter / denom;      // IEEE div; 0/0 -> NaN -> pred false
        const int pred = (iou >= NMS_THRE_) && (j != i) && (j < N_);
        if (pred) {
            const float4* cp = reinterpret_cast<const float4*>(con + ((size_t)b * N_ + j) * C_);
            const float4 c0 = cp[0], c1 = cp[1], c2 = cp[2], c3 = cp[3];
            cm[0]  = fmaxf(cm[0],  c0.x); cm[1]  = fmaxf(cm[1],  c0.y);
            cm[2]  = fmaxf(cm[2],  c0.z); cm[3]  = fmaxf(cm[3],  c0.w);
            cm[4]  = fmaxf(cm[4],  c1.x); cm[5]  = fmaxf(cm[5],  c1.y);
            cm[6]  = fmaxf(cm[6],  c1.z); cm[7]  = fmaxf(cm[7],  c1.w);
            cm[8]  = fmaxf(cm[8],  c2.x); cm[9]  = fmaxf(cm[9],  c2.y);
            cm[10] = fmaxf(cm[10], c2.z); cm[11] = fmaxf(cm[11], c2.w);
            cm[12] = fmaxf(cm[12], c3.x); cm[13] = fmaxf(cm[13], c3.y);
            cm[14] = fmaxf(cm[14], c3.z); cm[15] = fmaxf(cm[15], c3.w);
        }
        const u64 m = __ballot(pred);
        if (lane == 0) adj[((size_t)b * N_ + i) * NW_ + t] = m;
    }

#pragma unroll
    for (int off = 1; off < 64; off <<= 1) {
#pragma unroll
        for (int k = 0; k < C_; ++k) cm[k] = fmaxf(cm[k], __shfl_xor(cm[k], off));
    }
    if (lane == 0) {
        float4* o = reinterpret_cast<float4*>(adjcon + ((size_t)b * N_ + i) * C_);
        o[0] = make_float4(cm[0],  cm[1],  cm[2],  cm[3]);
        o[1] = make_float4(cm[4],  cm[5],  cm[6],  cm[7]);
        o[2] = make_float4(cm[8],  cm[9],  cm[10], cm[11]);
        o[3] = make_float4(cm[12], cm[13], cm[14], cm[15]);
    }
}

// ---------------------------------------------------------------------------
// K2: valid0 bitmask per (b,c): (pro>=conf) & (pro>=adj_con) & (pro>=con).
// One wave per 64-box word; ballot -> word.
// ---------------------------------------------------------------------------
__global__ __launch_bounds__(256) void k_valid0(const float* __restrict__ pro,
                                                const float* __restrict__ con,
                                                const float* __restrict__ adjcon,
                                                const float* __restrict__ conf,
                                                u64* __restrict__ valid) {
    const int tid  = threadIdx.x;
    const int lane = tid & 63;
    const int w    = blockIdx.x * 4 + (tid >> 6);   // 0 .. B*C*NW-1
    const int b    = w / (C_ * NW_);
    const int rem  = w % (C_ * NW_);
    const int c    = rem / NW_;
    const int t    = rem % NW_;
    const int i    = t * 64 + lane;
    int pred = 0;
    if (i < N_) {
        const size_t off = ((size_t)b * N_ + i) * C_ + c;
        const float p  = pro[off];
        const float cn = con[off];
        const float ac = adjcon[off];
        const float cf = conf[c];
        pred = (p >= cf) && (p >= ac) && (p >= cn);
    }
    const u64 m = __ballot(pred);
    if (lane == 0) valid[((size_t)b * C_ + c) * NW_ + t] = m;
}

// ---------------------------------------------------------------------------
// K3: per (b,c) stable descending argsort of pro scores.
// Composite u64 key = (~total_order_bits(score) << 32) | index, bitonic in LDS.
// Stable desc-by-score, asc-by-index == jnp.argsort(-scores).
// ---------------------------------------------------------------------------
__global__ __launch_bounds__(256) void k_sort(const float* __restrict__ pro,
                                              int* __restrict__ order) {
    __shared__ u64 keys[NSORT_];
    const int bc = blockIdx.x;
    const int b  = bc / C_, c = bc % C_;
    for (int i = threadIdx.x; i < NSORT_; i += 256) {
        u64 key = ~0ull;
        if (i < N_) {
            const u32 bits = __float_as_uint(pro[((size_t)b * N_ + i) * C_ + c]);
            const u32 m = bits ^ ((bits & 0x80000000u) ? 0xFFFFFFFFu : 0x80000000u);
            key = (((u64)(~m)) << 32) | (u32)i;
        }
        keys[i] = key;
    }
    __syncthreads();
    for (int k = 2; k <= NSORT_; k <<= 1) {
        for (int j = k >> 1; j > 0; j >>= 1) {
            for (int t = threadIdx.x; t < NSORT_; t += 256) {
                const int ixj = t ^ j;
                if (ixj > t) {
                    const u64 a = keys[t], bb = keys[ixj];
                    const bool up = ((t & k) == 0);
                    if ((a > bb) == up) { keys[t] = bb; keys[ixj] = a; }
                }
            }
            __syncthreads();
        }
    }
    for (int i = threadIdx.x; i < N_; i += 256)
        order[(size_t)bc * N_ + i] = (int)(keys[i] & 0xFFFFFFFFu);
}

// ---------------------------------------------------------------------------
// K4: greedy suppression per (b,c). One wave; lane w owns valid word w in a
// register. Sequential over sorted order; bit test via shuffles (uniform
// branch); on valid -> AND out adjacency row (57-word global load).
// In-place update of `valid` (read fully before write).
// ---------------------------------------------------------------------------
__global__ __launch_bounds__(64) void k_nms(const int* __restrict__ order,
                                            const u64* __restrict__ adj,
                                            u64* __restrict__ valid) {
    const int lane = threadIdx.x;
    const int bc   = blockIdx.x;
    const int b    = bc / C_;
    u64 myword = (lane < NW_) ? valid[(size_t)bc * NW_ + lane] : 0ull;
    int ordv = 0;
    for (int k = 0; k < N_; ++k) {
        if ((k & 63) == 0) {
            const int p = k + lane;
            ordv = (p < N_) ? order[(size_t)bc * N_ + p] : 0;
        }
        const int idx = __shfl(ordv, k & 63);
        const u64 wv  = __shfl(myword, idx >> 6);
        if ((wv >> (idx & 63)) & 1ull) {               // wave-uniform branch
            const u64 row = (lane < NW_) ? adj[((size_t)b * N_ + idx) * NW_ + lane] : 0ull;
            myword &= ~row;
        }
    }
    if (lane < NW_) valid[(size_t)bc * NW_ + lane] = myword;
}

// ---------------------------------------------------------------------------
// K5: output assembly. Survivors, in greedy-order sequence, compacted to the
// front (this IS the reference's argsort(-where(survive,score,-1e30)) since
// suppressed rows are exact zeros). d_out pre-zeroed by memset.
// ---------------------------------------------------------------------------
__global__ __launch_bounds__(64) void k_out(const int* __restrict__ order,
                                            const u64* __restrict__ valid,
                                            const float* __restrict__ boxes,
                                            const float* __restrict__ pro,
                                            const float* __restrict__ scales,
                                            float* __restrict__ out) {
#pragma clang fp contract(off)
    __shared__ u64 lv[NW_];
    const int lane = threadIdx.x;
    const int bc   = blockIdx.x;
    const int b    = bc / C_, c = bc % C_;
    if (lane < NW_) lv[lane] = valid[(size_t)bc * NW_ + lane];
    __syncthreads();
    const float s = scales[b];
    int S = 0;
    for (int t = 0; t < NW_; ++t) {
        const int k = t * 64 + lane;
        int flag = 0, idx = 0;
        if (k < N_) {
            idx  = order[(size_t)bc * N_ + k];
            flag = (int)((lv[idx >> 6] >> (idx & 63)) & 1ull);
        }
        const u64 m = __ballot(flag);
        if (flag) {
            const int pos = S + (int)__popcll(m & ((1ull << lane) - 1ull));
            const float4 bx = reinterpret_cast<const float4*>(boxes)[(size_t)b * N_ + idx];
            const float scx = bx.x * s, scy = bx.y * s, sw = bx.z * s, sh = bx.w * s;
            const float x1 = scx - 0.5f * sw;
            const float y1 = scy - 0.5f * sh;
            const float x2 = scx + 0.5f * sw;
            const float y2 = scy + 0.5f * sh;
            const float sc = pro[((size_t)b * N_ + idx) * C_ + c];
            float* o = out + ((size_t)bc * N_ + pos) * 5;
            o[0] = x1; o[1] = y1; o[2] = x2; o[3] = y2; o[4] = sc;
            out[(size_t)B_ * C_ * N_ * 5 + (size_t)bc * N_ + pos] = 1.0f;
        }
        S += (int)__popcll(m);
    }
}

// ---------------------------------------------------------------------------
extern "C" void kernel_launch(void* const* d_in, const int* in_sizes, int n_in,
                              void* d_out, int out_size, void* d_ws, size_t ws_size,
                              hipStream_t stream) {
    const float* pro    = (const float*)d_in[0];   // (B,N,C)
    const float* con    = (const float*)d_in[1];   // (B,N,C)
    const float* boxes  = (const float*)d_in[2];   // (B,N,4)
    const float* scales = (const float*)d_in[3];   // (B,)
    const float* conf   = (const float*)d_in[4];   // (C,)

    char* ws = (char*)d_ws;
    u64* adj = (u64*)ws;                                   // B*N*NW u64  (6.57 MB)
    size_t off = (size_t)B_ * N_ * NW_ * sizeof(u64);
    float* adjcon = (float*)(ws + off);                    // B*N*C f32   (0.92 MB)
    off += (size_t)B_ * N_ * C_ * sizeof(float);
    int* order = (int*)(ws + off);                         // B*C*N i32   (0.92 MB)
    off += (size_t)B_ * C_ * N_ * sizeof(int);
    u64* valid = (u64*)(ws + off);                         // B*C*NW u64  (29 KB)

    hipMemsetAsync(d_out, 0, (size_t)out_size * sizeof(float), stream);
    k_adj   <<<B_ * N_ / 4,        256, 0, stream>>>(boxes, con, adj, adjcon);
    k_valid0<<<B_ * C_ * NW_ / 4,  256, 0, stream>>>(pro, con, adjcon, conf, valid);
    k_sort  <<<B_ * C_,            256, 0, stream>>>(pro, order);
    k_nms   <<<B_ * C_,             64, 0, stream>>>(order, adj, valid);
    k_out   <<<B_ * C_,             64, 0, stream>>>(order, valid, boxes, pro, scales,
                                                     (float*)d_out);
}

// Round 2
// 522.126 us; speedup vs baseline: 1.7032x; 1.7032x over previous
//
#include <hip/hip_runtime.h>
#include <cstdint>

typedef unsigned long long u64;
typedef unsigned int u32;

#define B_ 4
#define N_ 3600
#define C_ 16
#define NW_ 57        // ceil(N/64) words of adjacency/valid bitmask
#define NPAD_ 3648    // NW_*64
#define NMS_THRE_ 0.4f

// ---------------------------------------------------------------------------
// K1: per image, per row i: adjacency bitmask (57 u64 words) via wave ballot,
// and adj_con[i][c] = max over adjacent j of con[j][c] (init 0 to match
// where(adj, con, 0)). One wave per row, 4 rows per 256-thread block.
// ---------------------------------------------------------------------------
__global__ __launch_bounds__(256) void k_adj(const float* __restrict__ boxes,
                                             const float* __restrict__ con,
                                             u64* __restrict__ adj,
                                             float* __restrict__ adjcon) {
#pragma clang fp contract(off)
    __shared__ float4 sbox[NPAD_];   // (x1,y1,x2,y2)
    const int tid  = threadIdx.x;
    const int lane = tid & 63;
    const int wv   = tid >> 6;
    const int g    = blockIdx.x;              // 0 .. B*N/4-1
    const int b    = g / (N_ / 4);
    const int r0   = (g % (N_ / 4)) * 4;

    for (int j = tid; j < NPAD_; j += 256) {
        float x1 = 0.f, y1 = 0.f, x2 = 0.f, y2 = 0.f;
        if (j < N_) {
            const float4 bx = reinterpret_cast<const float4*>(boxes)[(size_t)b * N_ + j];
            x1 = bx.x - bx.z * 0.5f;   // cx - w/2
            y1 = bx.y - bx.w * 0.5f;
            x2 = x1 + bx.z;            // x1 + w  (exact reference op order)
            y2 = y1 + bx.w;
        }
        sbox[j] = make_float4(x1, y1, x2, y2);
    }
    __syncthreads();

    const int    i  = r0 + wv;
    const float4 bi = sbox[i];
    const float  ai = (bi.z - bi.x) * (bi.w - bi.y);

    float cm[C_];
#pragma unroll
    for (int k = 0; k < C_; ++k) cm[k] = 0.0f;

    for (int t = 0; t < NW_; ++t) {
        const int    j  = t * 64 + lane;
        const float4 bj = sbox[j];
        const float  aj = (bj.z - bj.x) * (bj.w - bj.y);
        const float ltx = fmaxf(bi.x, bj.x);
        const float lty = fmaxf(bi.y, bj.y);
        const float rbx = fminf(bi.z, bj.z);
        const float rby = fminf(bi.w, bj.w);
        const float whx = fmaxf(rbx - ltx, 0.0f);
        const float why = fmaxf(rby - lty, 0.0f);
        const float inter = whx * why;
        const float denom = (ai + aj) - inter;
        const float iou   = inter / denom;      // IEEE div; 0/0 -> NaN -> pred false
        const int pred = (iou >= NMS_THRE_) && (j != i) && (j < N_);
        if (pred) {
            const float4* cp = reinterpret_cast<const float4*>(con + ((size_t)b * N_ + j) * C_);
            const float4 c0 = cp[0], c1 = cp[1], c2 = cp[2], c3 = cp[3];
            cm[0]  = fmaxf(cm[0],  c0.x); cm[1]  = fmaxf(cm[1],  c0.y);
            cm[2]  = fmaxf(cm[2],  c0.z); cm[3]  = fmaxf(cm[3],  c0.w);
            cm[4]  = fmaxf(cm[4],  c1.x); cm[5]  = fmaxf(cm[5],  c1.y);
            cm[6]  = fmaxf(cm[6],  c1.z); cm[7]  = fmaxf(cm[7],  c1.w);
            cm[8]  = fmaxf(cm[8],  c2.x); cm[9]  = fmaxf(cm[9],  c2.y);
            cm[10] = fmaxf(cm[10], c2.z); cm[11] = fmaxf(cm[11], c2.w);
            cm[12] = fmaxf(cm[12], c3.x); cm[13] = fmaxf(cm[13], c3.y);
            cm[14] = fmaxf(cm[14], c3.z); cm[15] = fmaxf(cm[15], c3.w);
        }
        const u64 m = __ballot(pred);
        if (lane == 0) adj[((size_t)b * N_ + i) * NW_ + t] = m;
    }

#pragma unroll
    for (int off = 1; off < 64; off <<= 1) {
#pragma unroll
        for (int k = 0; k < C_; ++k) cm[k] = fmaxf(cm[k], __shfl_xor(cm[k], off));
    }
    if (lane == 0) {
        float4* o = reinterpret_cast<float4*>(adjcon + ((size_t)b * N_ + i) * C_);
        o[0] = make_float4(cm[0],  cm[1],  cm[2],  cm[3]);
        o[1] = make_float4(cm[4],  cm[5],  cm[6],  cm[7]);
        o[2] = make_float4(cm[8],  cm[9],  cm[10], cm[11]);
        o[3] = make_float4(cm[12], cm[13], cm[14], cm[15]);
    }
}

// ---------------------------------------------------------------------------
// K2: fused valid0 -> compact candidate list -> sort -> greedy NMS -> output.
// One 64-thread block per (b,c).
//
// Correctness of candidate restriction: greedy suppression only CLEARS valid
// bits, so boxes outside valid0 can never suppress anything — iterating only
// over valid0 members in score order is exactly the reference loop.
// Output ordering: survivors in greedy (score desc, idx asc) order, compacted
// to the front; suppressed rows are exact zeros => identical to the
// reference's argsort(-where(survive, score, -1e30)) gather (stable ties).
// ---------------------------------------------------------------------------
__global__ __launch_bounds__(64) void k_select(const float* __restrict__ pro,
                                               const float* __restrict__ con,
                                               const float* __restrict__ adjcon,
                                               const float* __restrict__ conf,
                                               const u64* __restrict__ adj,
                                               const float* __restrict__ boxes,
                                               const float* __restrict__ scales,
                                               float* __restrict__ out) {
#pragma clang fp contract(off)
    __shared__ u64 keys[4096];          // (~score_bits << 32) | idx  (asc sort)
    __shared__ u64 vmask[NW_];
    const int lane = threadIdx.x;
    const int bc   = blockIdx.x;
    const int b    = bc / C_, c = bc % C_;
    const float cf = conf[c];

    // --- valid0 + compaction ---
    int T = 0;
    for (int t = 0; t < NW_; ++t) {
        const int i = t * 64 + lane;
        int pred = 0;
        u32 skey = 0;
        if (i < N_) {
            const size_t off = ((size_t)b * N_ + i) * C_ + c;
            const float p = pro[off];
            pred = (p >= cf) && (p >= adjcon[off]) && (p >= con[off]);
            const u32 bits = __float_as_uint(p);
            skey = bits ^ ((bits & 0x80000000u) ? 0xFFFFFFFFu : 0x80000000u);
        }
        const u64 m = __ballot(pred);
        if (lane == 0) vmask[t] = m;
        if (pred) {
            const int pos = T + (int)__popcll(m & ((1ull << lane) - 1ull));
            keys[pos] = (((u64)(~skey)) << 32) | (u32)i;
        }
        T += (int)__popcll(m);          // uniform across lanes
    }
    __syncthreads();

    // --- pad to next pow2 and bitonic sort (ascending => score desc, idx asc)
    int P = 2;
    while (P < T) P <<= 1;              // P <= 4096 (T <= 3600)
    for (int i = T + lane; i < P; i += 64) keys[i] = ~0ull;
    __syncthreads();
    for (int k = 2; k <= P; k <<= 1) {
        for (int j = k >> 1; j > 0; j >>= 1) {
            for (int t = lane; t < P; t += 64) {
                const int ixj = t ^ j;
                if (ixj > t) {
                    const u64 a = keys[t], bb = keys[ixj];
                    const bool up = ((t & k) == 0);
                    if ((a > bb) == up) { keys[t] = bb; keys[ixj] = a; }
                }
            }
            __syncthreads();
        }
    }

    // --- greedy suppression over the T candidates, emit survivors in order
    u64 myword = (lane < NW_) ? vmask[lane] : 0ull;
    const float s = scales[b];
    int S = 0;
    for (int t = 0; t < T; ++t) {
        const int idx = (int)(keys[t] & 0xFFFFFFFFull);   // LDS broadcast read
        const u64 wv  = __shfl(myword, idx >> 6);
        if ((wv >> (idx & 63)) & 1ull) {                  // wave-uniform branch
            const u64 row = (lane < NW_) ? adj[((size_t)b * N_ + idx) * NW_ + lane] : 0ull;
            myword &= ~row;                               // diag excluded; own bit stays
            if (lane == 0) {
                const float4 bx = reinterpret_cast<const float4*>(boxes)[(size_t)b * N_ + idx];
                const float scx = bx.x * s, scy = bx.y * s, sw = bx.z * s, sh = bx.w * s;
                float* o = out + ((size_t)bc * N_ + S) * 5;
                o[0] = scx - 0.5f * sw;
                o[1] = scy - 0.5f * sh;
                o[2] = scx + 0.5f * sw;
                o[3] = scy + 0.5f * sh;
                o[4] = pro[((size_t)b * N_ + idx) * C_ + c];
                out[(size_t)B_ * C_ * N_ * 5 + (size_t)bc * N_ + S] = 1.0f;
            }
            ++S;
        }
    }
}

// ---------------------------------------------------------------------------
extern "C" void kernel_launch(void* const* d_in, const int* in_sizes, int n_in,
                              void* d_out, int out_size, void* d_ws, size_t ws_size,
                              hipStream_t stream) {
    const float* pro    = (const float*)d_in[0];   // (B,N,C)
    const float* con    = (const float*)d_in[1];   // (B,N,C)
    const float* boxes  = (const float*)d_in[2];   // (B,N,4)
    const float* scales = (const float*)d_in[3];   // (B,)
    const float* conf   = (const float*)d_in[4];   // (C,)

    char* ws = (char*)d_ws;
    u64* adj = (u64*)ws;                                   // B*N*NW u64  (6.57 MB)
    size_t off = (size_t)B_ * N_ * NW_ * sizeof(u64);
    float* adjcon = (float*)(ws + off);                    // B*N*C f32   (0.92 MB)

    hipMemsetAsync(d_out, 0, (size_t)out_size * sizeof(float), stream);
    k_adj   <<<B_ * N_ / 4, 256, 0, stream>>>(boxes, con, adj, adjcon);
    k_select<<<B_ * C_,      64, 0, stream>>>(pro, con, adjcon, conf, adj, boxes,
                                              scales, (float*)d_out);
}

// Round 3
// 333.470 us; speedup vs baseline: 2.6667x; 1.5657x over previous
//
#include <hip/hip_runtime.h>
#include <cstdint>

typedef unsigned long long u64;
typedef unsigned int u32;

#define B_ 4
#define N_ 3600
#define C_ 16
#define NW_ 57        // ceil(N/64) words of adjacency/valid bitmask
#define NWP_ 64       // padded row stride (u64 words) -> unguarded 64-lane loads
#define NPAD_ 3648    // NW_*64

// ---------------------------------------------------------------------------
// K1: per image, per row i: adjacency bitmask (NW_ words, row stride NWP_)
// via wave ballot, and adj_con[i][c] = max over adjacent j of con[j][c].
// One wave per row, 4 rows per 256-thread block.
//
// Exact division-free IoU test:
//   pred_ref = ( round_f32(inter/denom) >= 0.4f )
//            = ( inter > (0.4f - 2^-26) * denom )  evaluated in f64:
//   inter,denom are f32 (exact in f64); MID has 26-bit mantissa; MID*denom
//   has <=50-bit mantissa -> exact. Tie at the midpoint rounds-to-even to
//   prev(0.4f) (even mantissa) < 0.4f -> false, matching strict '>'.
//   denom==0 => inter==0 => 0>0 false, matching 0/0=NaN >= 0.4 false.
// ---------------------------------------------------------------------------
__global__ __launch_bounds__(256) void k_adj(const float* __restrict__ boxes,
                                             const float* __restrict__ con,
                                             u64* __restrict__ adj,
                                             float* __restrict__ adjcon) {
#pragma clang fp contract(off)
    __shared__ float4 sbox[NPAD_];   // (x1,y1,x2,y2)
    __shared__ float  sarea[NPAD_];
    const int tid  = threadIdx.x;
    const int lane = tid & 63;
    const int wv   = tid >> 6;
    const int g    = blockIdx.x;              // 0 .. B*N/4-1
    const int b    = g / (N_ / 4);
    const int r0   = (g % (N_ / 4)) * 4;

    for (int j = tid; j < NPAD_; j += 256) {
        float x1 = 0.f, y1 = 0.f, x2 = 0.f, y2 = 0.f;
        if (j < N_) {
            const float4 bx = reinterpret_cast<const float4*>(boxes)[(size_t)b * N_ + j];
            x1 = bx.x - bx.z * 0.5f;   // cx - w/2
            y1 = bx.y - bx.w * 0.5f;
            x2 = x1 + bx.z;            // x1 + w  (exact reference op order)
            y2 = y1 + bx.w;
        }
        sbox[j]  = make_float4(x1, y1, x2, y2);
        sarea[j] = (x2 - x1) * (y2 - y1);
    }
    __syncthreads();

    const int    i  = r0 + wv;
    const float4 bi = sbox[i];
    const float  ai = sarea[i];
    const double MID = (double)0.4f - 0x1p-26;   // exact

    float cm[C_];
#pragma unroll
    for (int k = 0; k < C_; ++k) cm[k] = 0.0f;

    for (int t = 0; t < NW_; ++t) {
        const int    j  = t * 64 + lane;
        const float4 bj = sbox[j];
        const float  aj = sarea[j];
        const float ltx = fmaxf(bi.x, bj.x);
        const float lty = fmaxf(bi.y, bj.y);
        const float rbx = fminf(bi.z, bj.z);
        const float rby = fminf(bi.w, bj.w);
        const float whx = fmaxf(rbx - ltx, 0.0f);
        const float why = fmaxf(rby - lty, 0.0f);
        const float inter = whx * why;
        const float denom = (ai + aj) - inter;
        const int pred = ((double)inter > MID * (double)denom) && (j != i) && (j < N_);
        if (pred) {
            const float4* cp = reinterpret_cast<const float4*>(con + ((size_t)b * N_ + j) * C_);
            const float4 c0 = cp[0], c1 = cp[1], c2 = cp[2], c3 = cp[3];
            cm[0]  = fmaxf(cm[0],  c0.x); cm[1]  = fmaxf(cm[1],  c0.y);
            cm[2]  = fmaxf(cm[2],  c0.z); cm[3]  = fmaxf(cm[3],  c0.w);
            cm[4]  = fmaxf(cm[4],  c1.x); cm[5]  = fmaxf(cm[5],  c1.y);
            cm[6]  = fmaxf(cm[6],  c1.z); cm[7]  = fmaxf(cm[7],  c1.w);
            cm[8]  = fmaxf(cm[8],  c2.x); cm[9]  = fmaxf(cm[9],  c2.y);
            cm[10] = fmaxf(cm[10], c2.z); cm[11] = fmaxf(cm[11], c2.w);
            cm[12] = fmaxf(cm[12], c3.x); cm[13] = fmaxf(cm[13], c3.y);
            cm[14] = fmaxf(cm[14], c3.z); cm[15] = fmaxf(cm[15], c3.w);
        }
        const u64 m = __ballot(pred);
        if (lane == 0) adj[((size_t)b * N_ + i) * NWP_ + t] = m;
    }

#pragma unroll
    for (int off = 1; off < 64; off <<= 1) {
#pragma unroll
        for (int k = 0; k < C_; ++k) cm[k] = fmaxf(cm[k], __shfl_xor(cm[k], off));
    }
    if (lane == 0) {
        float4* o = reinterpret_cast<float4*>(adjcon + ((size_t)b * N_ + i) * C_);
        o[0] = make_float4(cm[0],  cm[1],  cm[2],  cm[3]);
        o[1] = make_float4(cm[4],  cm[5],  cm[6],  cm[7]);
        o[2] = make_float4(cm[8],  cm[9],  cm[10], cm[11]);
        o[3] = make_float4(cm[12], cm[13], cm[14], cm[15]);
    }
}

// ---------------------------------------------------------------------------
// K2: fused valid0 -> compact -> sort -> greedy NMS -> output, one block
// (256 threads) per (b,c). Greedy runs on wave 0 with a 16-deep register
// pipeline of adj rows (addresses depend only on sorted order, never on the
// valid state) and scalar readlane bit tests -> short critical chain.
// ---------------------------------------------------------------------------
__global__ __launch_bounds__(256) void k_select(const float* __restrict__ pro,
                                                const float* __restrict__ con,
                                                const float* __restrict__ adjcon,
                                                const float* __restrict__ conf,
                                                const u64* __restrict__ adj,
                                                const float* __restrict__ boxes,
                                                const float* __restrict__ scales,
                                                float* __restrict__ out) {
#pragma clang fp contract(off)
    __shared__ u64 keys[4096];          // (~score_bits << 32) | idx  (asc sort)
    __shared__ u64 vmask[NW_];
    __shared__ u32 slist[3648];         // survivor indices, greedy order
    __shared__ u32 s_cnt;
    __shared__ u32 s_S;
    const int tid  = threadIdx.x;
    const int lane = tid & 63;
    const int wv   = tid >> 6;
    const int bc   = blockIdx.x;
    const int b    = bc / C_, c = bc % C_;
    const float cf = conf[c];

    if (tid == 0) s_cnt = 0;
    __syncthreads();

    // --- phase 1: valid0 + unordered compaction (all 4 waves) ---
    for (int t = wv; t < NW_; t += 4) {
        const int i = t * 64 + lane;
        int pred = 0;
        u64 key = 0;
        if (i < N_) {
            const size_t off = ((size_t)b * N_ + i) * C_ + c;
            const float p = pro[off];
            pred = (p >= cf) && (p >= adjcon[off]) && (p >= con[off]);
            const u32 bits = __float_as_uint(p);
            const u32 m = bits ^ ((bits >> 31) ? 0xFFFFFFFFu : 0x80000000u);
            key = (((u64)(~m)) << 32) | (u32)i;
        }
        const u64 bm = __ballot(pred);
        if (lane == 0) vmask[t] = bm;
        u32 base = 0;
        if (lane == 0 && bm) base = atomicAdd(&s_cnt, (u32)__popcll(bm));
        base = (u32)__shfl((int)base, 0);
        if (pred) keys[base + (u32)__popcll(bm & ((1ull << lane) - 1ull))] = key;
    }
    __syncthreads();

    const int T = (int)s_cnt;
    int P = 2;
    while (P < T) P <<= 1;              // P <= 4096
    for (int i = T + tid; i < P; i += 256) keys[i] = ~0ull;
    __syncthreads();

    // --- phase 2: bitonic sort (ascending => score desc, idx asc), 256 thr ---
    for (int k = 2; k <= P; k <<= 1) {
        for (int j = k >> 1; j > 0; j >>= 1) {
            for (int t = tid; t < P; t += 256) {
                const int ixj = t ^ j;
                if (ixj > t) {
                    const u64 a = keys[t], bb = keys[ixj];
                    const bool up = ((t & k) == 0);
                    if ((a > bb) == up) { keys[t] = bb; keys[ixj] = a; }
                }
            }
            __syncthreads();
        }
    }

    // --- phase 3: greedy suppression (wave 0 only) ---
    if (wv == 0) {
        const u32* keys32 = (const u32*)keys;   // low word of keys[i] = idx
        const size_t bN = (size_t)b * N_;
        u64 myword = (lane < NW_) ? vmask[lane] : 0ull;
        u32 ordv = keys32[2 * lane];            // idx for candidates [0,64)
        u64 rowp[16];
        u32 idxp[16];
#pragma unroll
        for (int d = 0; d < 16; ++d) {
            const u32 idxn = (d < T) ? (u32)__builtin_amdgcn_readlane((int)ordv, d) : 0u;
            idxp[d] = idxn;
            rowp[d] = adj[(bN + idxn) * NWP_ + lane];
        }
        u32 S = 0;
        for (int k0 = 0; k0 < T; k0 += 16) {
#pragma unroll
            for (int d = 0; d < 16; ++d) {
                const int k = k0 + d;
                const u32 idx = idxp[d];
                const u64 row = rowp[d];        // load issued 16 iters ago
                // prefetch candidate k+16
                const int kn = k + 16;
                if ((kn & 63) == 0) ordv = keys32[2 * (kn + lane)];
                const u32 idxn = (kn < T) ? (u32)__builtin_amdgcn_readlane((int)ordv, kn & 63) : 0u;
                idxp[d] = idxn;
                rowp[d] = adj[(bN + idxn) * NWP_ + lane];
                // bit test via scalar readlane (wave-uniform, no LDS latency)
                const int  w   = (int)(idx >> 6);
                const u32  lo  = (u32)__builtin_amdgcn_readlane((int)(u32)myword, w);
                const u32  hi  = (u32)__builtin_amdgcn_readlane((int)(u32)(myword >> 32), w);
                const u32  sel = (idx & 32) ? hi : lo;
                u32 bit = (sel >> (idx & 31)) & 1u;
                bit &= (u32)(k < T);
                const u64 bm = bit ? ~0ull : 0ull;
                myword &= ~(row & bm);
                if (lane == 0) slist[bit ? S : 3647] = idx;
                S += bit;
            }
        }
        if (lane == 0) s_S = S;
    }
    __syncthreads();

    // --- phase 4: parallel output of survivors in greedy order ---
    const int S = (int)s_S;
    const float s = scales[b];
    for (int r = tid; r < S; r += 256) {
        const int idx = (int)slist[r];
        const float4 bx = reinterpret_cast<const float4*>(boxes)[(size_t)b * N_ + idx];
        const float scx = bx.x * s, scy = bx.y * s, sw = bx.z * s, sh = bx.w * s;
        float* o = out + ((size_t)bc * N_ + r) * 5;
        o[0] = scx - 0.5f * sw;
        o[1] = scy - 0.5f * sh;
        o[2] = scx + 0.5f * sw;
        o[3] = scy + 0.5f * sh;
        o[4] = pro[((size_t)b * N_ + idx) * C_ + c];
        out[(size_t)B_ * C_ * N_ * 5 + (size_t)bc * N_ + r] = 1.0f;
    }
}

// ---------------------------------------------------------------------------
extern "C" void kernel_launch(void* const* d_in, const int* in_sizes, int n_in,
                              void* d_out, int out_size, void* d_ws, size_t ws_size,
                              hipStream_t stream) {
    const float* pro    = (const float*)d_in[0];   // (B,N,C)
    const float* con    = (const float*)d_in[1];   // (B,N,C)
    const float* boxes  = (const float*)d_in[2];   // (B,N,4)
    const float* scales = (const float*)d_in[3];   // (B,)
    const float* conf   = (const float*)d_in[4];   // (C,)

    char* ws = (char*)d_ws;
    u64* adj = (u64*)ws;                                   // B*N*NWP u64 (7.37 MB)
    size_t off = (size_t)B_ * N_ * NWP_ * sizeof(u64);
    float* adjcon = (float*)(ws + off);                    // B*N*C f32   (0.92 MB)

    hipMemsetAsync(d_out, 0, (size_t)out_size * sizeof(float), stream);
    k_adj   <<<B_ * N_ / 4, 256, 0, stream>>>(boxes, con, adj, adjcon);
    k_select<<<B_ * C_,     256, 0, stream>>>(pro, con, adjcon, conf, adj, boxes,
                                              scales, (float*)d_out);
}